// Round 7
// baseline (172.221 us; speedup 1.0000x reference)
//
#include <hip/hip_runtime.h>
#include <math.h>

// v12b: DIAGNOSTIC resubmit (r6 bench was an infra failure: container
// acquisition failed twice; no kernel verdict). Identical to v12.
//
// v12: zero-LDS. Rows loaded global->VGPR, partner rows via DPP.
// Evidence: v6/v8/v10/v11 (4 different structures, occupancies 12-20 w/CU,
// different instr mixes) ALL land at 47-48us kernel, VALUBusy pinned ~39%.
// Pipe integrals: VALU ~19us, HBM ~8-17us, LDS ~10us -- wall 48us means
// waves stall CORRELATED on a shared path. The only never-varied element:
// the global_load_lds -> WAITVM -> ds_read round-trip. v12 removes it:
//  (1) 2 lanes/sample (q = conv-row parity), 32 samples/wave; each lane
//      loads its 5 own-parity rows (50 floats) via 25 independent
//      global_load_dwordx2 -> 25-deep MLP, per-use waits, no barrier.
//  (2) 6 partner-parity rows per batch via dpp_swap1 exchange (no memory).
//  (3) compute body = v8's proven filter-packed conv + packed deconv tail.
//  (4) LDS_Block_Size = 0; occupancy VGPR-bound only (~130 VGPR).
// Fork: LDS was binder -> ~25-32us kernel. Unchanged -> tail is binder.
// FETCH>>110MB + regression -> scattered loads over-fetch, revert staging.

typedef float v2f __attribute__((ext_vector_type(2)));

#define SREAD(x) __int_as_float(__builtin_amdgcn_readfirstlane(__float_as_int(x)))

__device__ __forceinline__ float dpp_swap1_f(float x) {      // lane ^ 1
    return __int_as_float(__builtin_amdgcn_mov_dpp(__float_as_int(x), 0xB1, 0xF, 0xF, true));
}
__device__ __forceinline__ unsigned dpp_swap1_u(unsigned x) {
    return (unsigned)__builtin_amdgcn_mov_dpp((int)x, 0xB1, 0xF, 0xF, true);
}

__global__ __launch_bounds__(256, 3) void CNN2D_37495064494620_kernel(
    const float* __restrict__ v,
    const float* __restrict__ cw,   // [4,1,3,3]
    const float* __restrict__ cb,   // [4]
    const float* __restrict__ dw,   // [4,1,2,2]
    const float* __restrict__ db,   // [1]
    float* __restrict__ out,        // [2*B]
    int B)
{
    const int lane = threadIdx.x & 63;
    const int wv   = threadIdx.x >> 6;    // wave in block (0..3)
    const int q    = lane & 1;            // conv-row parity
    const int sl   = lane >> 1;           // sample within wave (0..31)
    const int s    = blockIdx.x * 128 + wv * 32 + sl;

    // ---- issue row loads FIRST: 5 own-parity rows = 25 dwordx2, all
    //      independent (addresses 8B-aligned: row offset = (2k+q)*40B) ----
    const float* my = v + (size_t)s * 100;
    float R[5][10];
    #pragma unroll
    for (int k = 0; k < 5; ++k) {
        const float* rp = my + (2 * k + q) * 10;
        #pragma unroll
        for (int t = 0; t < 5; ++t) {
            const float2 x = *(const float2*)(rp + 2 * t);
            R[k][2 * t] = x.x; R[k][2 * t + 1] = x.y;
        }
    }

    // ---- uniform weights -> SGPRs (overlaps the 25 loads in flight) ----
    float Wf[4][9];
    #pragma unroll
    for (int f = 0; f < 4; ++f)
        #pragma unroll
        for (int t = 0; t < 9; ++t)
            Wf[f][t] = SREAD(cw[f * 9 + t]);
    v2f W2[9][2];                         // taps packed (f0,f1),(f2,f3)
    #pragma unroll
    for (int t = 0; t < 9; ++t) {
        W2[t][0] = (v2f){Wf[0][t], Wf[1][t]};
        W2[t][1] = (v2f){Wf[2][t], Wf[3][t]};
    }
    const v2f Cb2[2] = { (v2f){SREAD(cb[0]), SREAD(cb[1])},
                         (v2f){SREAD(cb[2]), SREAD(cb[3])} };
    float Dw4[4][4];
    #pragma unroll
    for (int f = 0; f < 4; ++f)
        #pragma unroll
        for (int t = 0; t < 4; ++t)
            Dw4[f][t] = SREAD(dw[f * 4 + t]);
    const float Db = SREAD(db[0]);
    // this lane's deconv kl-pair (2q, 2q+1), packed
    v2f Dq[4];
    #pragma unroll
    for (int f = 0; f < 4; ++f)
        Dq[f] = (v2f){ q ? Dw4[f][2] : Dw4[f][0], q ? Dw4[f][3] : Dw4[f][1] };

    // ---- partner-row exchange state (rotating buffers, static parity) ----
    // r0(0): q=0 wants row9 = partner(q1) R[4]; q=1 wants row0 = partner(q0) R[0].
    float X0[10], X1[10];
    #pragma unroll
    for (int e = 0; e < 10; ++e) {
        const float t = q ? R[4][e] : R[0][e];   // what THIS lane presents
        X0[e] = dpp_swap1_f(t);                  // partner's presentation
    }

    unsigned sbits = 0u;   // XOR of this lane's z sign bits
    float l2 = 0.0f;       // this lane's partial sum of log2|z|

    #pragma unroll
    for (int i = 0; i < 5; ++i) {
        float* Xp = (i & 1) ? X1 : X0;   // r0(i), already filled
        float* Xn = (i & 1) ? X0 : X1;   // r2(i), fill now (becomes r0(i+1))
        // r2(i): q=0 wants partner R[i]; q=1 wants partner R[(i+1)%5].
        // So this lane PRESENTS: q=0 -> R[(i+1)%5], q=1 -> R[i].
        #pragma unroll
        for (int e = 0; e < 10; ++e) {
            const float t = q ? R[i][e] : R[(i + 1) % 5][e];
            Xn[e] = dpp_swap1_f(t);
        }
        const float* R0 = Xp;
        const float* R1 = R[i];          // own center row 2i+q
        const float* R2 = Xn;

        #pragma unroll
        for (int j = 0; j < 5; ++j) {
            // conv at cols 2j (a0) and 2j+1 (a1), all 4 filters packed in pairs
            v2f a0[2] = {Cb2[0], Cb2[1]};
            v2f a1[2] = {Cb2[0], Cb2[1]};
            #pragma unroll
            for (int kr = 0; kr < 3; ++kr) {
                const float* Rr = (kr == 0) ? R0 : ((kr == 1) ? R1 : R2);
                #pragma unroll
                for (int kc = 0; kc < 3; ++kc) {
                    const int cc0 = (2 * j + kc + 9) % 10;       // compile-time
                    const int cc1 = (2 * j + 1 + kc + 9) % 10;
                    const int t = kr * 3 + kc;
                    const v2f x0 = (v2f){Rr[cc0], Rr[cc0]};
                    const v2f x1 = (v2f){Rr[cc1], Rr[cc1]};
                    a0[0] = __builtin_elementwise_fma(x0, W2[t][0], a0[0]);
                    a0[1] = __builtin_elementwise_fma(x0, W2[t][1], a0[1]);
                    a1[0] = __builtin_elementwise_fma(x1, W2[t][0], a1[0]);
                    a1[1] = __builtin_elementwise_fma(x1, W2[t][1], a1[1]);
                }
            }
            // 2x2 maxpool: dc-merge packed, cross-row (lane pair) via DPP
            const v2f m0 = __builtin_elementwise_max(a0[0], a1[0]);
            const v2f m1 = __builtin_elementwise_max(a0[1], a1[1]);
            float P[4];
            P[0] = fmaxf(m0.x, dpp_swap1_f(m0.x));
            P[1] = fmaxf(m0.y, dpp_swap1_f(m0.y));
            P[2] = fmaxf(m1.x, dpp_swap1_f(m1.x));
            P[3] = fmaxf(m1.y, dpp_swap1_f(m1.y));

            // deconv: this lane owns kl = 2q, 2q+1 (packed)
            v2f z2 = (v2f){Db, Db};
            #pragma unroll
            for (int f = 0; f < 4; ++f) {
                const v2f pf = (v2f){P[f], P[f]};
                z2 = __builtin_elementwise_fma(pf, Dq[f], z2);
            }
            const float zp = z2.x * z2.y;        // pair product -> one log
            sbits ^= __float_as_uint(zp);
            l2 += __log2f(fabsf(zp));
        }
    }

    // combine across the lane pair (both lanes end with totals)
    l2 = l2 + dpp_swap1_f(l2);
    sbits = sbits ^ dpp_swap1_u(sbits);

    if (q == 0) out[s]     = (sbits & 0x80000000u) ? -1.0f : 1.0f;
    else        out[B + s] = l2 * 0.69314718055994531f;
}

extern "C" void kernel_launch(void* const* d_in, const int* in_sizes, int n_in,
                              void* d_out, int out_size, void* d_ws, size_t ws_size,
                              hipStream_t stream) {
    const float* v  = (const float*)d_in[0];
    const float* cw = (const float*)d_in[1];
    const float* cb = (const float*)d_in[2];
    const float* dw = (const float*)d_in[3];
    const float* db = (const float*)d_in[4];
    float* out = (float*)d_out;

    const int B = in_sizes[0] / 100;       // 262144
    const int grid = B / 128;              // 128 samples per 256-thread block
    CNN2D_37495064494620_kernel<<<grid, 256, 0, stream>>>(v, cw, cb, dw, db, out, B);
}

// Round 8
// 168.058 us; speedup vs baseline: 1.0248x; 1.0248x over previous
//
#include <hip/hip_runtime.h>
#include <math.h>

// v13: ILP test -- two independent 16-sample streams interleaved per wave.
//
// Evidence: v6/v8/v10/v11/v12 (LDS-staged x4, zero-LDS x1; occupancy
// 1.7-6.5 waves/SIMD; per-lane pk count halved in v11) ALL land at 47-50us,
// VALUBusy pinned ~39%. Per-wave duty HALVES as occupancy doubles ->
// shared-resource saturation OR per-wave dependency latency. The one axis
// never varied: per-wave ILP -- every version ran ONE serial chain per
// position (conv->DPP pool->deconv->log, ~100cy latency, ~50 instr).
// v13 = v8's proven structure + both batches computed INTERLEAVED:
//  (1) 64-thr blocks, quad mapping (q,h,g), 32 samples staged up front.
//  (2) each (i,j) body computes stream A then stream B -- two independent
//      dep chains; scheduler fills A's stalls with B's instructions.
//  (3) no VGPR cap (v9 lesson: forced caps spill); expect ~110-130 VGPR,
//      LDS 12.8KB/1-wave block -> 12 blocks/CU = 12 waves/CU (as v6/v8).
// Fork: latency-bound -> ~28-33us kernel; unchanged -> VALU-pipe floor,
// declare roofline; dur>180 -> spill, cap and retry.

typedef float v2f __attribute__((ext_vector_type(2)));

#define SREAD(x) __int_as_float(__builtin_amdgcn_readfirstlane(__float_as_int(x)))
#define WAITVM(N) asm volatile("s_waitcnt vmcnt(" #N ")" ::: "memory")

__device__ __forceinline__ float dpp_swap1_f(float x) {      // lane ^ 1
    return __int_as_float(__builtin_amdgcn_mov_dpp(__float_as_int(x), 0xB1, 0xF, 0xF, true));
}
__device__ __forceinline__ float dpp_swap2_f(float x) {      // lane ^ 2
    return __int_as_float(__builtin_amdgcn_mov_dpp(__float_as_int(x), 0x4E, 0xF, 0xF, true));
}
__device__ __forceinline__ unsigned dpp_swap1_u(unsigned x) {
    return (unsigned)__builtin_amdgcn_mov_dpp((int)x, 0xB1, 0xF, 0xF, true);
}
__device__ __forceinline__ unsigned dpp_swap2_u(unsigned x) {
    return (unsigned)__builtin_amdgcn_mov_dpp((int)x, 0x4E, 0xF, 0xF, true);
}

__device__ __forceinline__ void gload16(const float* g, float* l) {
    __builtin_amdgcn_global_load_lds(
        (const __attribute__((address_space(1))) void*)g,
        (__attribute__((address_space(3))) void*)l, 16, 0, 0);
}
__device__ __forceinline__ void gload4(const float* g, float* l) {
    __builtin_amdgcn_global_load_lds(
        (const __attribute__((address_space(1))) void*)g,
        (__attribute__((address_space(3))) void*)l, 4, 0, 0);
}

__global__ __launch_bounds__(64) void CNN2D_37495064494620_kernel(
    const float* __restrict__ v,
    const float* __restrict__ cw,   // [4,1,3,3]
    const float* __restrict__ cb,   // [4]
    const float* __restrict__ dw,   // [4,1,2,2]
    const float* __restrict__ db,   // [1]
    float* __restrict__ out,        // [2*B]
    int B)
{
    const int lane = threadIdx.x;         // one wave per block
    const int q    = lane & 1;            // conv-row parity
    const int h    = (lane >> 1) & 1;     // filter-pair owner (f0,f1 | f2,f3)
    const int g    = lane >> 2;           // sample within each 16-sample batch

    __shared__ __align__(16) float sm[3200];   // 2 batches x 16 samples x 100

    // ---- stage both batches up front: 14 gload_lds, one drain ----
    const float* gb = v + (size_t)blockIdx.x * 3200;
    #pragma unroll
    for (int k = 0; k < 6; ++k)
        gload16(gb + k * 256 + lane * 4, sm + k * 256);
    gload4(gb + 1536 + lane, sm + 1536);
    #pragma unroll
    for (int k = 0; k < 6; ++k)
        gload16(gb + 1600 + k * 256 + lane * 4, sm + 1600 + k * 256);
    gload4(gb + 3136 + lane, sm + 3136);

    // ---- uniform weights -> SGPRs (overlap the VMEM flight); v8 verbatim ----
    float Wf[4][9];
    #pragma unroll
    for (int f = 0; f < 4; ++f)
        #pragma unroll
        for (int t = 0; t < 9; ++t)
            Wf[f][t] = SREAD(cw[f * 9 + t]);
    v2f Wsel[9];
    #pragma unroll
    for (int t = 0; t < 9; ++t)
        Wsel[t] = (v2f){ h ? Wf[2][t] : Wf[0][t], h ? Wf[3][t] : Wf[1][t] };
    const float cb0 = SREAD(cb[0]), cb1 = SREAD(cb[1]);
    const float cb2 = SREAD(cb[2]), cb3 = SREAD(cb[3]);
    const v2f Cbsel = (v2f){ h ? cb2 : cb0, h ? cb3 : cb1 };

    float Dw4[4][4];
    #pragma unroll
    for (int f = 0; f < 4; ++f)
        #pragma unroll
        for (int t = 0; t < 4; ++t)
            Dw4[f][t] = SREAD(dw[f * 4 + t]);
    const float Db = SREAD(db[0]);
    float Dkl[4];                         // this lane's tap kl = 2q+h
    #pragma unroll
    for (int f = 0; f < 4; ++f) {
        const float e01 = h ? Dw4[f][1] : Dw4[f][0];
        const float e23 = h ? Dw4[f][3] : Dw4[f][2];
        Dkl[f] = q ? e23 : e01;
    }
    const float Ds0 = h ? Dkl[2] : Dkl[0];   // own filter pair first
    const float Ds1 = h ? Dkl[3] : Dkl[1];
    const float Ds2 = h ? Dkl[0] : Dkl[2];
    const float Ds3 = h ? Dkl[1] : Dkl[3];

    WAITVM(0);   // all 14 staging loads landed

    const float* myA = sm + g * 100;
    const float* myB = sm + 1600 + g * 100;

    unsigned sbA = 0u, sbB = 0u;
    float l2A = 0.0f, l2B = 0.0f;
    float zpA = 0.0f, zpB = 0.0f;

    #pragma unroll
    for (int i = 0; i < 5; ++i) {
        // conv row r1 = 2i+q; window rows r1-1, r1, r1+1 (wrap)
        const int r1 = 2 * i + q;
        const int r0 = (i == 0) ? (q ? 0 : 9) : (2 * i - 1 + q);
        const int r2 = (i == 4) ? (q ? 0 : 9) : (2 * i + 1 + q);

        float RA[3][10], RB[3][10];
        #pragma unroll
        for (int t = 0; t < 5; ++t) {
            float2 a0v = *(const float2*)(myA + r0 * 10 + 2 * t);
            float2 a1v = *(const float2*)(myA + r1 * 10 + 2 * t);
            float2 a2v = *(const float2*)(myA + r2 * 10 + 2 * t);
            RA[0][2 * t] = a0v.x; RA[0][2 * t + 1] = a0v.y;
            RA[1][2 * t] = a1v.x; RA[1][2 * t + 1] = a1v.y;
            RA[2][2 * t] = a2v.x; RA[2][2 * t + 1] = a2v.y;
            float2 b0v = *(const float2*)(myB + r0 * 10 + 2 * t);
            float2 b1v = *(const float2*)(myB + r1 * 10 + 2 * t);
            float2 b2v = *(const float2*)(myB + r2 * 10 + 2 * t);
            RB[0][2 * t] = b0v.x; RB[0][2 * t + 1] = b0v.y;
            RB[1][2 * t] = b1v.x; RB[1][2 * t + 1] = b1v.y;
            RB[2][2 * t] = b2v.x; RB[2][2 * t + 1] = b2v.y;
        }

        #pragma unroll
        for (int j = 0; j < 5; ++j) {
            const int pos = i * 5 + j;     // compile-time after unroll

            // ---- both streams' convs first (8 independent fma chains) ----
            v2f a0A = Cbsel, a1A = Cbsel, a0B = Cbsel, a1B = Cbsel;
            #pragma unroll
            for (int kr = 0; kr < 3; ++kr) {
                #pragma unroll
                for (int kc = 0; kc < 3; ++kc) {
                    const int cc0 = (2 * j + kc + 9) % 10;       // compile-time
                    const int cc1 = (2 * j + 1 + kc + 9) % 10;
                    const int t = kr * 3 + kc;
                    const v2f xA0 = (v2f){RA[kr][cc0], RA[kr][cc0]};
                    const v2f xA1 = (v2f){RA[kr][cc1], RA[kr][cc1]};
                    a0A = __builtin_elementwise_fma(xA0, Wsel[t], a0A);
                    a1A = __builtin_elementwise_fma(xA1, Wsel[t], a1A);
                    const v2f xB0 = (v2f){RB[kr][cc0], RB[kr][cc0]};
                    const v2f xB1 = (v2f){RB[kr][cc1], RB[kr][cc1]};
                    a0B = __builtin_elementwise_fma(xB0, Wsel[t], a0B);
                    a1B = __builtin_elementwise_fma(xB1, Wsel[t], a1B);
                }
            }

            // ---- interleaved tails (two independent serial chains) ----
            const v2f mA = __builtin_elementwise_max(a0A, a1A);
            const v2f mB = __builtin_elementwise_max(a0B, a1B);
            const float PxA = fmaxf(mA.x, dpp_swap1_f(mA.x));
            const float PxB = fmaxf(mB.x, dpp_swap1_f(mB.x));
            const float PyA = fmaxf(mA.y, dpp_swap1_f(mA.y));
            const float PyB = fmaxf(mB.y, dpp_swap1_f(mB.y));
            const float QxA = dpp_swap2_f(PxA);
            const float QxB = dpp_swap2_f(PxB);
            const float QyA = dpp_swap2_f(PyA);
            const float QyB = dpp_swap2_f(PyB);

            float zA = Db, zB = Db;
            zA = fmaf(PxA, Ds0, zA);  zB = fmaf(PxB, Ds0, zB);
            zA = fmaf(PyA, Ds1, zA);  zB = fmaf(PyB, Ds1, zB);
            zA = fmaf(QxA, Ds2, zA);  zB = fmaf(QxB, Ds2, zB);
            zA = fmaf(QyA, Ds3, zA);  zB = fmaf(QyB, Ds3, zB);

            if (pos == 24) {
                sbA ^= __float_as_uint(zA);
                l2A += __log2f(fabsf(zA));
                sbB ^= __float_as_uint(zB);
                l2B += __log2f(fabsf(zB));
            } else if (pos & 1) {
                const float zpa = zpA * zA;
                const float zpb = zpB * zB;
                sbA ^= __float_as_uint(zpa);
                sbB ^= __float_as_uint(zpb);
                l2A += __log2f(fabsf(zpa));
                l2B += __log2f(fabsf(zpb));
            } else {
                zpA = zA;
                zpB = zB;
            }
        }
    }

    // quad combine both streams: all 4 lanes end with both totals
    l2A += dpp_swap1_f(l2A);  l2B += dpp_swap1_f(l2B);
    l2A += dpp_swap2_f(l2A);  l2B += dpp_swap2_f(l2B);
    sbA ^= dpp_swap1_u(sbA);  sbB ^= dpp_swap1_u(sbB);
    sbA ^= dpp_swap2_u(sbA);  sbB ^= dpp_swap2_u(sbB);

    const int sA = blockIdx.x * 32 + g;       // stream A sample
    const int sB = sA + 16;                   // stream B sample
    const int r = lane & 3;
    if (r == 0)      out[sA]     = (sbA & 0x80000000u) ? -1.0f : 1.0f;
    else if (r == 1) out[B + sA] = l2A * 0.69314718055994531f;
    else if (r == 2) out[sB]     = (sbB & 0x80000000u) ? -1.0f : 1.0f;
    else             out[B + sB] = l2B * 0.69314718055994531f;
}

extern "C" void kernel_launch(void* const* d_in, const int* in_sizes, int n_in,
                              void* d_out, int out_size, void* d_ws, size_t ws_size,
                              hipStream_t stream) {
    const float* v  = (const float*)d_in[0];
    const float* cw = (const float*)d_in[1];
    const float* cb = (const float*)d_in[2];
    const float* dw = (const float*)d_in[3];
    const float* db = (const float*)d_in[4];
    float* out = (float*)d_out;

    const int B = in_sizes[0] / 100;       // 262144
    const int grid = B / 32;               // 32 samples per one-wave block
    CNN2D_37495064494620_kernel<<<grid, 64, 0, stream>>>(v, cw, cb, dw, db, out, B);
}